// Round 8
// baseline (197.432 us; speedup 1.0000x reference)
//
#include <hip/hip_runtime.h>
#include <math.h>

#define DT   0.1f
#define HDT  0.005f
#define T_HIST 20
#define LEN_PRED 30

typedef __attribute__((ext_vector_type(8))) short bfrag8;   // 8 bf16 = 4 VGPRs
typedef __attribute__((ext_vector_type(4))) float f32x4;
typedef __attribute__((ext_vector_type(2))) unsigned int u32x2;

// d_ws layout (bytes)
#define WS_FRAG   0u        // 96 frags * 512 bf16 * 2B = 98304
#define WS_WIN    98304u    // 2 frags * 1024B (w-major: frag w = Win rows w*16..w*16+15)
#define WS_WOUT   100352u   // 1 frag * 1024B (replicated rows -> pred0..3 in every lane)
#define WS_BIAS   101376u   // 2*3*32*4 floats = 3072B ([ph][l][col][gate])

static __device__ __forceinline__ unsigned short f2bf(float x) {
    union { float f; unsigned int u; } v; v.f = x;
    unsigned int r = v.u + 0x7fffu + ((v.u >> 16) & 1u);   // RNE
    return (unsigned short)(r >> 16);
}

static __device__ __forceinline__ unsigned int cvtpk(float lo, float hi) {
    unsigned int r;
    asm("v_cvt_pk_bf16_f32 %0, %1, %2" : "=v"(r) : "v"(lo), "v"(hi));
    return r;
}

// ---------------- weight prep (UNCHANGED from R7) ----------------
// Layer frag (ph,l,c,t): A[p][k] = W[gate*32+feat][k],
// gate=p&3, feat = (t>>1)*8 + 2*(p>>2) + (t&1).
// D-layout row=q*4+r -> lane (q,m) reg r = gate r of cell feat (t>>1)*8+2q+(t&1).
// Win frag (w-major): frag w rows p -> Win row w*16+p.
// Wout frag: REPLICATED rows (p&3) -> every lane's D regs = pred0..3 (no shfl).
// Bias: [ph][l][col=feat][gate] -> one f32x4 C-in per (l,tile).
__global__ void prep_kernel(const float* __restrict__ Win_W,
                            const float* __restrict__ eWih, const float* __restrict__ eWhh,
                            const float* __restrict__ ebih, const float* __restrict__ ebhh,
                            const float* __restrict__ dWih, const float* __restrict__ dWhh,
                            const float* __restrict__ dbih, const float* __restrict__ dbhh,
                            const float* __restrict__ Wout_W,
                            char* __restrict__ ws)
{
    int i = blockIdx.x * blockDim.x + threadIdx.x;
    if (i < 49152) {
        int fi = i >> 9, within = i & 511;
        int lane = within >> 3, jj = within & 7;
        int t = fi & 7, c = (fi >> 3) & 1;
        int pl = fi >> 4;                 // ph*3 + l
        int l = pl % 3, ph = pl / 3;
        int p = lane & 15, q2 = lane >> 4;
        int gate = p & 3;
        int feat = (t >> 1) * 8 + 2 * (p >> 2) + (t & 1);
        int row = gate * 32 + feat;
        int k = q2 * 8 + jj;
        const float* W = (c == 0) ? (ph ? dWih : eWih) : (ph ? dWhh : eWhh);
        ((unsigned short*)(ws + WS_FRAG))[i] = f2bf(W[l * 4096 + row * 32 + k]);
    } else if (i < 50176) {
        int i2 = i - 49152;
        int w = i2 >> 9, within = i2 & 511;
        int lane = within >> 3, jj = within & 7;
        int p = lane & 15, q2 = lane >> 4;
        int k = q2 * 8 + jj;
        float v = (k < 24) ? Win_W[(w * 16 + p) * 24 + k] : 0.f;
        ((unsigned short*)(ws + WS_WIN))[i2] = f2bf(v);
    } else if (i < 50688) {
        int i3 = i - 50176;
        int lane = i3 >> 3, jj = i3 & 7;
        int p = lane & 15, q2 = lane >> 4;
        float v = Wout_W[(p & 3) * 32 + q2 * 8 + jj];   // replicated rows
        ((unsigned short*)(ws + WS_WOUT))[i3] = f2bf(v);
    } else if (i < 51456) {
        int b = i - 50688;                 // [ph][l][col][r]
        int ph = b / 384, rem = b % 384;
        int l = rem >> 7, w2 = rem & 127;
        int col = w2 >> 2, r = w2 & 3;
        const float* bi = ph ? dbih : ebih;
        const float* bh = ph ? dbhh : ebhh;
        ((float*)(ws + WS_BIAS))[b] = bi[l * 128 + r * 32 + col] + bh[l * 128 + r * 32 + col];
    }
}

// ---------------- main kernel: 8 waves per 16 batch elems ----------------
// Wave wv owns ONE tile (cell feat (wv>>1)*8+2q+(wv&1) per lane per layer).
// Waves 6,7 also run the KF with BOTH channels in registers (XP fragment built
// in-register, no LDS staging). 16 waves/CU (2 blocks) vs 8 before — the
// latency-hiding this kernel was missing. Diagonal encoder (21 barriers),
// replicated-Wout shfl-free decoder, hoisted hh-MFMAs retained.
__launch_bounds__(512, 4)
__global__ void kalman_lstm_kernel(const float* __restrict__ hist,
                                   const float* __restrict__ max_ax, const float* __restrict__ max_ay,
                                   const float* __restrict__ vstd, const float* __restrict__ astd,
                                   const float* __restrict__ Rx_, const float* __restrict__ Ry_,
                                   const float* __restrict__ Gx, const float* __restrict__ Gy,
                                   const float* __restrict__ Win_b, const float* __restrict__ Wout_b,
                                   const char* __restrict__ ws, float* __restrict__ out)
{
    __shared__ __align__(16) unsigned int xchC[3][2][4][16][4]; // [layer][parity][fg][m][dw]
    __shared__ __align__(16) unsigned int xchH[3][2][4][16][4];
    __shared__ __align__(16) unsigned int xenc[T_HIST - 1][4][16][4]; // encoder x0 frags
    __shared__ __align__(16) unsigned int x0b[4][16][4];             // decoder x0 frag

    const int tid  = threadIdx.x;
    const int wv   = tid >> 6;        // 0..7 = tile id; waves 6,7 also KF
    const int lane = tid & 63;
    const int q    = lane >> 4;
    const int m    = lane & 15;
    const int be   = blockIdx.x * 16 + m;
    const f32x4 zero4 = {0.f, 0.f, 0.f, 0.f};

    const bfrag8* fragp = (const bfrag8*)(ws + WS_FRAG);
    const f32x4*  biasp = (const f32x4*)(ws + WS_BIAS);

    // ---- per-wave weights: ONE tile -> [l][c: 0=ih 1=hh] ----
    bfrag8 fragA[3][2];
    f32x4  biasV[3];
    auto load_phase = [&](int ph) {
#pragma unroll
        for (int l = 0; l < 3; ++l) {
#pragma unroll
            for (int c = 0; c < 2; ++c)
                fragA[l][c] = fragp[(((ph * 3 + l) * 2 + c) * 8 + wv) * 64 + lane];
            biasV[l] = biasp[ph * 96 + l * 32 + ((wv >> 1) * 8 + 2 * q + (wv & 1))];
        }
    };
    load_phase(0);

    // ---- KF-wave operators (waves 6,7; w = wv-6) ----
    const int w = (wv >= 6) ? (wv - 6) : 0;
    bfrag8 winF = ((const bfrag8*)(ws + WS_WIN))[w * 64 + lane];
    f32x4 winBv;
#pragma unroll
    for (int r = 0; r < 4; ++r) winBv[r] = Win_b[w * 16 + q * 4 + r];
    bfrag8 woutF = ((const bfrag8*)(ws + WS_WOUT))[lane];
    const float wb0 = Wout_b[0], wb1 = Wout_b[1], wb2 = Wout_b[2], wb3 = Wout_b[3];

    // ---- uniform KF constants (wave-uniform -> SGPRs) ----
    const float rx = Rx_[0] * Rx_[0], ry = Ry_[0] * Ry_[0];
    const float gX0 = Gx[0], gX1 = Gx[1], gX2 = Gx[2];
    const float gY0 = Gy[0], gY1 = Gy[1], gY2 = Gy[2];
    const float gx00 = gX0*gX0, gx01 = gX0*gX1, gx02 = gX0*gX2,
                gx11 = gX1*gX1, gx12 = gX1*gX2, gx22 = gX2*gX2;
    const float gy00 = gY0*gY0, gy01 = gY0*gY1, gy02 = gY0*gY2,
                gy11 = gY1*gY1, gy12 = gY1*gY2, gy22 = gY2*gY2;
    const float sx2 = max_ax[0] * max_ax[0], sy2 = max_ay[0] * max_ay[0];
    const float ex00 = gx00*sx2, ex01 = gx01*sx2, ex02 = gx02*sx2,
                ex11 = gx11*sx2, ex12 = gx12*sx2, ex22 = gx22*sx2;
    const float ey00 = gy00*sy2, ey01 = gy01*sy2, ey02 = gy02*sy2,
                ey11 = gy11*sy2, ey12 = gy12*sy2, ey22 = gy22*sy2;
    const float pv = vstd[0] * vstd[0], pa = astd[0] * astd[0];

    // ---- KF state, BOTH channels per lane (live in waves 6,7) ----
    float Xx0 = hist[be * 40 + 0], Xx1 = 0.f, Xx2 = 0.f;
    float Xy0 = hist[be * 40 + 1], Xy1 = 0.f, Xy2 = 0.f;
    float Px00 = rx, Px01 = 0.f, Px02 = 0.f, Px11 = pv, Px12 = 0.f, Px22 = pa;
    float Py00 = rx, Py01 = 0.f, Py02 = 0.f, Py11 = pv, Py12 = 0.f, Py22 = pa;  // ref kinit: R_x both

    float creg[3] = {0.f, 0.f, 0.f};

    auto sig = [](float z) { return __builtin_amdgcn_rcpf(1.f + __expf(-z)); };
    auto th  = [](float z) { return fmaf(-2.f, __builtin_amdgcn_rcpf(__expf(2.f * z) + 1.f), 1.f); };

    auto kpred9 = [](float& X0, float& X1, float& X2,
                     float& P00, float& P01, float& P02, float& P11, float& P12, float& P22,
                     float Q00, float Q01, float Q02, float Q11, float Q12, float Q22) {
        X0 = X0 + DT * X1 + HDT * X2;
        X1 = X1 + DT * X2;
        float M00 = P00 + DT * P01 + HDT * P02;
        float M01 = P01 + DT * P11 + HDT * P12;
        float M02 = P02 + DT * P12 + HDT * P22;
        float M11 = P11 + DT * P12;
        float M12 = P12 + DT * P22;
        float M22 = P22;
        P00 = M00 + DT * M01 + HDT * M02 + Q00;
        P01 = M01 + DT * M02 + Q01;
        P02 = M02 + Q02;
        P11 = M11 + DT * M12 + Q11;
        P12 = M12 + Q12;
        P22 = M22 + Q22;
    };
    auto kupd9 = [](float& X0, float& X1, float& X2,
                    float& P00, float& P01, float& P02, float& P11, float& P12, float& P22,
                    float z, float R) {
        float y = z - X0;
        float Sinv = 1.0f / (P00 + R);
        float K0 = P00 * Sinv, K1 = P01 * Sinv, K2 = P02 * Sinv;
        X0 += y * K0; X1 += y * K1; X2 += y * K2;
        float p00 = P00, p01 = P01, p02 = P02;
        P00 = p00 - K0 * p00;
        P01 = p01 - K0 * p01;
        P02 = p02 - K0 * p02;
        P11 = P11 - K1 * p01;
        P12 = P12 - K1 * p02;
        P22 = P22 - K2 * p02;
    };
    auto kf_enc_step = [&](int s) {
        float zx = hist[be * 40 + s * 2], zy = hist[be * 40 + s * 2 + 1];
        kpred9(Xx0, Xx1, Xx2, Px00, Px01, Px02, Px11, Px12, Px22, ex00, ex01, ex02, ex11, ex12, ex22);
        kupd9 (Xx0, Xx1, Xx2, Px00, Px01, Px02, Px11, Px12, Px22, zx, rx);
        kpred9(Xy0, Xy1, Xy2, Py00, Py01, Py02, Py11, Py12, Py22, ey00, ey01, ey02, ey11, ey12, ey22);
        kupd9 (Xy0, Xy1, Xy2, Py00, Py01, Py02, Py11, Py12, Py22, zy, ry);
    };

    auto packf = [&](const float* v) {
        union { bfrag8 f; unsigned int u[4]; } u;
#pragma unroll
        for (int d = 0; d < 4; ++d) u.u[d] = cvtpk(v[2 * d], v[2 * d + 1]);
        return u.f;
    };
    // XP = [Xx(3), Xy(3), Px flat(9), Py flat(9), pad]; lane supplies elems 8q..8q+7
    auto build_xp = [&]() {
        float v[8];
        if (q == 0)      { v[0]=Xx0;  v[1]=Xx1;  v[2]=Xx2;  v[3]=Xy0;  v[4]=Xy1;  v[5]=Xy2;  v[6]=Px00; v[7]=Px01; }
        else if (q == 1) { v[0]=Px02; v[1]=Px01; v[2]=Px11; v[3]=Px12; v[4]=Px02; v[5]=Px12; v[6]=Px22; v[7]=Py00; }
        else if (q == 2) { v[0]=Py01; v[1]=Py02; v[2]=Py01; v[3]=Py11; v[4]=Py12; v[5]=Py02; v[6]=Py12; v[7]=Py22; }
        else             { v[0]=0.f; v[1]=0.f; v[2]=0.f; v[3]=0.f; v[4]=0.f; v[5]=0.f; v[6]=0.f; v[7]=0.f; }
        return packf(v);
    };
    // KF wave w: Win MFMA from in-register XP -> x0 feats w*16+q*4+{0..3} -> dst
    auto win_emit = [&](unsigned int* dst) {
        bfrag8 xpf = build_xp();
        f32x4 aw = __builtin_amdgcn_mfma_f32_16x16x32_bf16(winF, xpf, winBv, 0, 0, 0);
        u32x2 pk;
        pk.x = cvtpk(th(aw[0]), th(aw[1]));
        pk.y = cvtpk(th(aw[2]), th(aw[3]));
        *(u32x2*)(dst + ((2 * w + (q >> 1)) * 16 + m) * 4 + (q & 1) * 2) = pk;
    };

    // one LSTM cell for this wave's tile at layer l; b16 c/h writes (2-way, free)
    const int sidx = ((wv >> 1) * 16 + m) * 8 + 2 * q + (wv & 1);
    auto cell = [&](int l, bfrag8 xf, bfrag8 hf, unsigned int* Cb, unsigned int* Hb) {
        f32x4 a = __builtin_amdgcn_mfma_f32_16x16x32_bf16(fragA[l][1], hf, biasV[l], 0, 0, 0);
        a = __builtin_amdgcn_mfma_f32_16x16x32_bf16(fragA[l][0], xf, a, 0, 0, 0);
        float iv = sig(a[0]), fv = sig(a[1]), gv = th(a[2]), ov = sig(a[3]);
        float c = fmaf(fv, creg[l], iv * gv);
        creg[l] = c;
        float h = ov * th(c);
        unsigned int pk = cvtpk(c, h);
        ((unsigned short*)Cb)[sidx] = (unsigned short)pk;
        ((unsigned short*)Hb)[sidx] = (unsigned short)(pk >> 16);
    };

    bfrag8 c2f = bfrag8{};
    auto do_pred = [&](int tout) {
        f32x4 ap = __builtin_amdgcn_mfma_f32_16x16x32_bf16(woutF, c2f, zero4, 0, 0, 0);
        float p0 = ap[0] + wb0, p1 = ap[1] + wb1, p2 = ap[2] + wb2, p3 = ap[3] + wb3;
        Xx2 = DT * p0; Xy2 = DT * p1;
        float qsx = p2 * p2, qsy = p3 * p3;
        kpred9(Xx0, Xx1, Xx2, Px00, Px01, Px02, Px11, Px12, Px22,
               qsx*gx00, qsx*gx01, qsx*gx02, qsx*gx11, qsx*gx12, qsx*gx22);
        kpred9(Xy0, Xy1, Xy2, Py00, Py01, Py02, Py11, Py12, Py22,
               qsy*gy00, qsy*gy01, qsy*gy02, qsy*gy11, qsy*gy12, qsy*gy22);
        if (wv == 6 && q == 0) {
            float* o = out + (size_t)be * (LEN_PRED * 5) + tout * 5;
            o[0] = Xx0; o[1] = Xy0; o[2] = sqrtf(Px00); o[3] = sqrtf(Py00); o[4] = 0.f;
        }
    };

    // ---- LDS zero init (h,c = 0 for both parities) ----
    for (int i = tid; i < 3 * 2 * 4 * 16 * 4; i += 512) {
        (&xchC[0][0][0][0][0])[i] = 0;
        (&xchH[0][0][0][0][0])[i] = 0;
    }

    // ---- prologue: waves 6,7 run encoder KF + Win fully in-register ----
    if (wv >= 6) {
#pragma unroll 1
        for (int s = 0; s < T_HIST - 1; ++s) {
            if (s > 0) kf_enc_step(s);
            win_emit(&xenc[s][0][0][0]);
        }
        kf_enc_step(T_HIST - 1);   // z_19 -> decoder-initial KF state (stays in regs)
    }
    __syncthreads();               // xenc + zero-init visible

    // ---- encoder: diagonal pipeline, phases p = 0..20, ONE barrier each ----
#pragma unroll 1
    for (int p = 0; p < T_HIST + 1; ++p) {
        const int pw = p & 1, pr = pw ^ 1;
        if (p <= T_HIST - 2) {
            bfrag8 xf = *(const bfrag8*)&xenc[p][q][m][0];
            bfrag8 hf = *(const bfrag8*)&xchH[0][pr][q][m][0];
            cell(0, xf, hf, &xchC[0][pw][0][0][0], &xchH[0][pw][0][0][0]);
        }
        if (p >= 1 && p <= T_HIST - 1) {
            bfrag8 xf = *(const bfrag8*)&xchC[0][pr][q][m][0];
            bfrag8 hf = *(const bfrag8*)&xchH[1][pr][q][m][0];
            cell(1, xf, hf, &xchC[1][pw][0][0][0], &xchH[1][pw][0][0][0]);
        }
        if (p >= 2) {
            bfrag8 xf = *(const bfrag8*)&xchC[1][pr][q][m][0];
            bfrag8 hf = *(const bfrag8*)&xchH[2][pr][q][m][0];
            cell(2, xf, hf, &xchC[2][pw][0][0][0], &xchH[2][pw][0][0][0]);
        }
        __syncthreads();
    }

    // ---- transition: final h frags / c2 from pipeline parities ----
    // h0[18] @p18(par0), h1[18] @p19(par1), h2[18]/c2[18] @p20(par0)
    load_phase(1);
    bfrag8 hfragR[3];
    hfragR[0] = *(const bfrag8*)&xchH[0][0][q][m][0];
    hfragR[1] = *(const bfrag8*)&xchH[1][1][q][m][0];
    hfragR[2] = *(const bfrag8*)&xchH[2][0][q][m][0];
    c2f       = *(const bfrag8*)&xchC[2][0][q][m][0];
    // (first decoder write to these buffers is after bar1 -> reads are safe)

    // ---- decoder: 30 steps, 4 barriers/step ----
#pragma unroll 1
    for (int t = 0; t < LEN_PRED; ++t) {
        f32x4 ah[3];
#pragma unroll
        for (int l = 0; l < 3; ++l)    // hoisted hh-MFMAs (h(t-1) in registers)
            ah[l] = __builtin_amdgcn_mfma_f32_16x16x32_bf16(fragA[l][1], hfragR[l], biasV[l], 0, 0, 0);

        if (wv >= 6) {
            if (t > 0) do_pred(t - 1); // Wout (replicated) -> KF pred -> out store
            win_emit(&x0b[0][0][0]);   // XP in regs -> Win MFMA -> x0
        }
        __syncthreads();   // bar1: x0 visible

        bfrag8 xf = *(const bfrag8*)&x0b[q][m][0];
#pragma unroll
        for (int l = 0; l < 3; ++l) {
            f32x4 a = __builtin_amdgcn_mfma_f32_16x16x32_bf16(fragA[l][0], xf, ah[l], 0, 0, 0);
            float iv = sig(a[0]), fv = sig(a[1]), gv = th(a[2]), ov = sig(a[3]);
            float c = fmaf(fv, creg[l], iv * gv);
            creg[l] = c;
            float h = ov * th(c);
            unsigned int pk = cvtpk(c, h);
            ((unsigned short*)&xchC[l][0][0][0][0])[sidx] = (unsigned short)pk;
            ((unsigned short*)&xchH[l][0][0][0][0])[sidx] = (unsigned short)(pk >> 16);
            __syncthreads();   // bar2..4
            xf        = *(const bfrag8*)&xchC[l][0][q][m][0];
            hfragR[l] = *(const bfrag8*)&xchH[l][0][q][m][0];
        }
        c2f = xf;
    }
    if (wv >= 6) do_pred(LEN_PRED - 1);
}

extern "C" void kernel_launch(void* const* d_in, const int* in_sizes, int n_in,
                              void* d_out, int out_size, void* d_ws, size_t ws_size,
                              hipStream_t stream)
{
    const float* hist  = (const float*)d_in[0];
    const float* maxax = (const float*)d_in[1];
    const float* maxay = (const float*)d_in[2];
    const float* vstd  = (const float*)d_in[3];
    const float* astd  = (const float*)d_in[4];
    const float* Rx    = (const float*)d_in[5];
    const float* Ry    = (const float*)d_in[6];
    const float* Gx    = (const float*)d_in[7];
    const float* Gy    = (const float*)d_in[8];
    const float* WinW  = (const float*)d_in[9];
    const float* Winb  = (const float*)d_in[10];
    const float* eWih  = (const float*)d_in[11];
    const float* eWhh  = (const float*)d_in[12];
    const float* ebih  = (const float*)d_in[13];
    const float* ebhh  = (const float*)d_in[14];
    const float* dWih  = (const float*)d_in[15];
    const float* dWhh  = (const float*)d_in[16];
    const float* dbih  = (const float*)d_in[17];
    const float* dbhh  = (const float*)d_in[18];
    const float* WoutW = (const float*)d_in[19];
    const float* Woutb = (const float*)d_in[20];
    char* ws = (char*)d_ws;
    float* out = (float*)d_out;

    prep_kernel<<<202, 256, 0, stream>>>(WinW, eWih, eWhh, ebih, ebhh,
                                         dWih, dWhh, dbih, dbhh, WoutW, ws);
    kalman_lstm_kernel<<<512, 512, 0, stream>>>(hist, maxax, maxay, vstd, astd,
                                                Rx, Ry, Gx, Gy, Winb, Woutb,
                                                ws, out);
}

// Round 9
// 195.484 us; speedup vs baseline: 1.0100x; 1.0100x over previous
//
#include <hip/hip_runtime.h>
#include <math.h>

#define DT   0.1f
#define HDT  0.005f
#define T_HIST 20
#define LEN_PRED 30

typedef __attribute__((ext_vector_type(8))) short bfrag8;   // 8 bf16 = 4 VGPRs
typedef __attribute__((ext_vector_type(4))) float f32x4;
typedef __attribute__((ext_vector_type(2))) unsigned int u32x2;

// d_ws layout (bytes)
#define WS_FRAG   0u        // 96 frags * 512 bf16 * 2B = 98304
#define WS_WIN    98304u    // 2 frags * 1024B (w-major: frag w = Win rows w*16..w*16+15)
#define WS_WOUT   100352u   // 1 frag * 1024B (replicated rows -> pred0..3 in every lane)
#define WS_BIAS   101376u   // 2*3*32*4 floats = 3072B ([ph][l][col][gate])

static __device__ __forceinline__ unsigned short f2bf(float x) {
    union { float f; unsigned int u; } v; v.f = x;
    unsigned int r = v.u + 0x7fffu + ((v.u >> 16) & 1u);   // RNE
    return (unsigned short)(r >> 16);
}

static __device__ __forceinline__ unsigned int cvtpk(float lo, float hi) {
    unsigned int r;
    asm("v_cvt_pk_bf16_f32 %0, %1, %2" : "=v"(r) : "v"(lo), "v"(hi));
    return r;
}

// ---------------- weight prep (UNCHANGED from R7/R8) ----------------
// Layer frag (ph,l,c,t): A[p][k] = W[gate*32+feat][k],
// gate=p&3, feat = (t>>1)*8 + 2*(p>>2) + (t&1).
// D-layout row=q*4+r -> lane (q,m) reg r = gate r of cell feat (t>>1)*8+2q+(t&1).
// Win frag (w-major): frag w rows p -> Win row w*16+p.
// Wout frag: REPLICATED rows (p&3) -> every lane's D regs = pred0..3 (no shfl).
// Bias: [ph][l][col=feat][gate] -> one f32x4 C-in per (l,tile).
__global__ void prep_kernel(const float* __restrict__ Win_W,
                            const float* __restrict__ eWih, const float* __restrict__ eWhh,
                            const float* __restrict__ ebih, const float* __restrict__ ebhh,
                            const float* __restrict__ dWih, const float* __restrict__ dWhh,
                            const float* __restrict__ dbih, const float* __restrict__ dbhh,
                            const float* __restrict__ Wout_W,
                            char* __restrict__ ws)
{
    int i = blockIdx.x * blockDim.x + threadIdx.x;
    if (i < 49152) {
        int fi = i >> 9, within = i & 511;
        int lane = within >> 3, jj = within & 7;
        int t = fi & 7, c = (fi >> 3) & 1;
        int pl = fi >> 4;                 // ph*3 + l
        int l = pl % 3, ph = pl / 3;
        int p = lane & 15, q2 = lane >> 4;
        int gate = p & 3;
        int feat = (t >> 1) * 8 + 2 * (p >> 2) + (t & 1);
        int row = gate * 32 + feat;
        int k = q2 * 8 + jj;
        const float* W = (c == 0) ? (ph ? dWih : eWih) : (ph ? dWhh : eWhh);
        ((unsigned short*)(ws + WS_FRAG))[i] = f2bf(W[l * 4096 + row * 32 + k]);
    } else if (i < 50176) {
        int i2 = i - 49152;
        int w = i2 >> 9, within = i2 & 511;
        int lane = within >> 3, jj = within & 7;
        int p = lane & 15, q2 = lane >> 4;
        int k = q2 * 8 + jj;
        float v = (k < 24) ? Win_W[(w * 16 + p) * 24 + k] : 0.f;
        ((unsigned short*)(ws + WS_WIN))[i2] = f2bf(v);
    } else if (i < 50688) {
        int i3 = i - 50176;
        int lane = i3 >> 3, jj = i3 & 7;
        int p = lane & 15, q2 = lane >> 4;
        float v = Wout_W[(p & 3) * 32 + q2 * 8 + jj];   // replicated rows
        ((unsigned short*)(ws + WS_WOUT))[i3] = f2bf(v);
    } else if (i < 51456) {
        int b = i - 50688;                 // [ph][l][col][r]
        int ph = b / 384, rem = b % 384;
        int l = rem >> 7, w2 = rem & 127;
        int col = w2 >> 2, r = w2 & 3;
        const float* bi = ph ? dbih : ebih;
        const float* bh = ph ? dbhh : ebhh;
        ((float*)(ws + WS_BIAS))[b] = bi[l * 128 + r * 32 + col] + bh[l * 128 + r * 32 + col];
    }
}

// ---------------- main kernel: 8 waves per 16 batch elems ----------------
// R8 structure (16 waves/CU) with the register budget PINNED: waves_per_eu(4,4)
// -> VGPR budget exactly 128, forbidding the backend's 64-VGPR/8-wave squeeze
// that spilled fragA/bias/state to scratch (R8: WRITE_SIZE 4.8->12.2 MB).
__attribute__((amdgpu_waves_per_eu(4, 4)))
__launch_bounds__(512)
__global__ void kalman_lstm_kernel(const float* __restrict__ hist,
                                   const float* __restrict__ max_ax, const float* __restrict__ max_ay,
                                   const float* __restrict__ vstd, const float* __restrict__ astd,
                                   const float* __restrict__ Rx_, const float* __restrict__ Ry_,
                                   const float* __restrict__ Gx, const float* __restrict__ Gy,
                                   const float* __restrict__ Win_b, const float* __restrict__ Wout_b,
                                   const char* __restrict__ ws, float* __restrict__ out)
{
    __shared__ __align__(16) unsigned int xchC[3][2][4][16][4]; // [layer][parity][fg][m][dw]
    __shared__ __align__(16) unsigned int xchH[3][2][4][16][4];
    __shared__ __align__(16) unsigned int xenc[T_HIST - 1][4][16][4]; // encoder x0 frags
    __shared__ __align__(16) unsigned int x0b[4][16][4];             // decoder x0 frag

    const int tid  = threadIdx.x;
    const int wv   = tid >> 6;        // 0..7 = tile id; waves 6,7 also KF
    const int lane = tid & 63;
    const int q    = lane >> 4;
    const int m    = lane & 15;
    const int be   = blockIdx.x * 16 + m;
    const f32x4 zero4 = {0.f, 0.f, 0.f, 0.f};

    const bfrag8* fragp = (const bfrag8*)(ws + WS_FRAG);
    const f32x4*  biasp = (const f32x4*)(ws + WS_BIAS);

    // ---- per-wave weights: ONE tile -> [l][c: 0=ih 1=hh] ----
    bfrag8 fragA[3][2];
    f32x4  biasV[3];
    auto load_phase = [&](int ph) {
#pragma unroll
        for (int l = 0; l < 3; ++l) {
#pragma unroll
            for (int c = 0; c < 2; ++c)
                fragA[l][c] = fragp[(((ph * 3 + l) * 2 + c) * 8 + wv) * 64 + lane];
            biasV[l] = biasp[ph * 96 + l * 32 + ((wv >> 1) * 8 + 2 * q + (wv & 1))];
        }
    };
    load_phase(0);

    // ---- KF-wave operators (waves 6,7; w = wv-6) ----
    const int w = (wv >= 6) ? (wv - 6) : 0;
    bfrag8 winF = bfrag8{}, woutF = bfrag8{};
    f32x4 winBv = zero4;
    float wb0 = 0.f, wb1 = 0.f, wb2 = 0.f, wb3 = 0.f;

    // ---- uniform KF constants (wave-uniform -> SGPRs) ----
    const float rx = Rx_[0] * Rx_[0], ry = Ry_[0] * Ry_[0];
    const float gX0 = Gx[0], gX1 = Gx[1], gX2 = Gx[2];
    const float gY0 = Gy[0], gY1 = Gy[1], gY2 = Gy[2];
    const float gx00 = gX0*gX0, gx01 = gX0*gX1, gx02 = gX0*gX2,
                gx11 = gX1*gX1, gx12 = gX1*gX2, gx22 = gX2*gX2;
    const float gy00 = gY0*gY0, gy01 = gY0*gY1, gy02 = gY0*gY2,
                gy11 = gY1*gY1, gy12 = gY1*gY2, gy22 = gY2*gY2;
    const float sx2 = max_ax[0] * max_ax[0], sy2 = max_ay[0] * max_ay[0];
    const float ex00 = gx00*sx2, ex01 = gx01*sx2, ex02 = gx02*sx2,
                ex11 = gx11*sx2, ex12 = gx12*sx2, ex22 = gx22*sx2;
    const float ey00 = gy00*sy2, ey01 = gy01*sy2, ey02 = gy02*sy2,
                ey11 = gy11*sy2, ey12 = gy12*sy2, ey22 = gy22*sy2;
    const float pv = vstd[0] * vstd[0], pa = astd[0] * astd[0];

    // ---- KF state, BOTH channels per lane (live only in waves 6,7) ----
    float Xx0 = 0.f, Xx1 = 0.f, Xx2 = 0.f;
    float Xy0 = 0.f, Xy1 = 0.f, Xy2 = 0.f;
    float Px00 = 0.f, Px01 = 0.f, Px02 = 0.f, Px11 = 0.f, Px12 = 0.f, Px22 = 0.f;
    float Py00 = 0.f, Py01 = 0.f, Py02 = 0.f, Py11 = 0.f, Py12 = 0.f, Py22 = 0.f;
    if (wv >= 6) {
        winF  = ((const bfrag8*)(ws + WS_WIN))[w * 64 + lane];
        woutF = ((const bfrag8*)(ws + WS_WOUT))[lane];
#pragma unroll
        for (int r = 0; r < 4; ++r) winBv[r] = Win_b[w * 16 + q * 4 + r];
        wb0 = Wout_b[0]; wb1 = Wout_b[1]; wb2 = Wout_b[2]; wb3 = Wout_b[3];
        Xx0 = hist[be * 40 + 0];
        Xy0 = hist[be * 40 + 1];
        Px00 = rx; Px11 = pv; Px22 = pa;
        Py00 = rx; Py11 = pv; Py22 = pa;   // ref kinit: R_x both channels
    }

    float creg[3] = {0.f, 0.f, 0.f};

    auto sig = [](float z) { return __builtin_amdgcn_rcpf(1.f + __expf(-z)); };
    auto th  = [](float z) { return fmaf(-2.f, __builtin_amdgcn_rcpf(__expf(2.f * z) + 1.f), 1.f); };

    auto kpred9 = [](float& X0, float& X1, float& X2,
                     float& P00, float& P01, float& P02, float& P11, float& P12, float& P22,
                     float Q00, float Q01, float Q02, float Q11, float Q12, float Q22) {
        X0 = X0 + DT * X1 + HDT * X2;
        X1 = X1 + DT * X2;
        float M00 = P00 + DT * P01 + HDT * P02;
        float M01 = P01 + DT * P11 + HDT * P12;
        float M02 = P02 + DT * P12 + HDT * P22;
        float M11 = P11 + DT * P12;
        float M12 = P12 + DT * P22;
        float M22 = P22;
        P00 = M00 + DT * M01 + HDT * M02 + Q00;
        P01 = M01 + DT * M02 + Q01;
        P02 = M02 + Q02;
        P11 = M11 + DT * M12 + Q11;
        P12 = M12 + Q12;
        P22 = M22 + Q22;
    };
    auto kupd9 = [](float& X0, float& X1, float& X2,
                    float& P00, float& P01, float& P02, float& P11, float& P12, float& P22,
                    float z, float R) {
        float y = z - X0;
        float Sinv = 1.0f / (P00 + R);
        float K0 = P00 * Sinv, K1 = P01 * Sinv, K2 = P02 * Sinv;
        X0 += y * K0; X1 += y * K1; X2 += y * K2;
        float p00 = P00, p01 = P01, p02 = P02;
        P00 = p00 - K0 * p00;
        P01 = p01 - K0 * p01;
        P02 = p02 - K0 * p02;
        P11 = P11 - K1 * p01;
        P12 = P12 - K1 * p02;
        P22 = P22 - K2 * p02;
    };
    auto kf_enc_step = [&](int s) {
        float zx = hist[be * 40 + s * 2], zy = hist[be * 40 + s * 2 + 1];
        kpred9(Xx0, Xx1, Xx2, Px00, Px01, Px02, Px11, Px12, Px22, ex00, ex01, ex02, ex11, ex12, ex22);
        kupd9 (Xx0, Xx1, Xx2, Px00, Px01, Px02, Px11, Px12, Px22, zx, rx);
        kpred9(Xy0, Xy1, Xy2, Py00, Py01, Py02, Py11, Py12, Py22, ey00, ey01, ey02, ey11, ey12, ey22);
        kupd9 (Xy0, Xy1, Xy2, Py00, Py01, Py02, Py11, Py12, Py22, zy, ry);
    };

    auto packf = [&](const float* v) {
        union { bfrag8 f; unsigned int u[4]; } u;
#pragma unroll
        for (int d = 0; d < 4; ++d) u.u[d] = cvtpk(v[2 * d], v[2 * d + 1]);
        return u.f;
    };
    // XP = [Xx(3), Xy(3), Px flat(9), Py flat(9), pad]; lane supplies elems 8q..8q+7
    auto build_xp = [&]() {
        float v[8];
        if (q == 0)      { v[0]=Xx0;  v[1]=Xx1;  v[2]=Xx2;  v[3]=Xy0;  v[4]=Xy1;  v[5]=Xy2;  v[6]=Px00; v[7]=Px01; }
        else if (q == 1) { v[0]=Px02; v[1]=Px01; v[2]=Px11; v[3]=Px12; v[4]=Px02; v[5]=Px12; v[6]=Px22; v[7]=Py00; }
        else if (q == 2) { v[0]=Py01; v[1]=Py02; v[2]=Py01; v[3]=Py11; v[4]=Py12; v[5]=Py02; v[6]=Py12; v[7]=Py22; }
        else             { v[0]=0.f; v[1]=0.f; v[2]=0.f; v[3]=0.f; v[4]=0.f; v[5]=0.f; v[6]=0.f; v[7]=0.f; }
        return packf(v);
    };
    // KF wave w: Win MFMA from in-register XP -> x0 feats w*16+q*4+{0..3} -> dst
    auto win_emit = [&](unsigned int* dst) {
        bfrag8 xpf = build_xp();
        f32x4 aw = __builtin_amdgcn_mfma_f32_16x16x32_bf16(winF, xpf, winBv, 0, 0, 0);
        u32x2 pk;
        pk.x = cvtpk(th(aw[0]), th(aw[1]));
        pk.y = cvtpk(th(aw[2]), th(aw[3]));
        *(u32x2*)(dst + ((2 * w + (q >> 1)) * 16 + m) * 4 + (q & 1) * 2) = pk;
    };

    // one LSTM cell for this wave's tile at layer l; b16 c/h writes (2-way, free)
    const int sidx = ((wv >> 1) * 16 + m) * 8 + 2 * q + (wv & 1);
    auto cell = [&](int l, bfrag8 xf, bfrag8 hf, unsigned int* Cb, unsigned int* Hb) {
        f32x4 a = __builtin_amdgcn_mfma_f32_16x16x32_bf16(fragA[l][1], hf, biasV[l], 0, 0, 0);
        a = __builtin_amdgcn_mfma_f32_16x16x32_bf16(fragA[l][0], xf, a, 0, 0, 0);
        float iv = sig(a[0]), fv = sig(a[1]), gv = th(a[2]), ov = sig(a[3]);
        float c = fmaf(fv, creg[l], iv * gv);
        creg[l] = c;
        float h = ov * th(c);
        unsigned int pk = cvtpk(c, h);
        ((unsigned short*)Cb)[sidx] = (unsigned short)pk;
        ((unsigned short*)Hb)[sidx] = (unsigned short)(pk >> 16);
    };

    bfrag8 c2f = bfrag8{};
    auto do_pred = [&](int tout) {
        f32x4 ap = __builtin_amdgcn_mfma_f32_16x16x32_bf16(woutF, c2f, zero4, 0, 0, 0);
        float p0 = ap[0] + wb0, p1 = ap[1] + wb1, p2 = ap[2] + wb2, p3 = ap[3] + wb3;
        Xx2 = DT * p0; Xy2 = DT * p1;
        float qsx = p2 * p2, qsy = p3 * p3;
        kpred9(Xx0, Xx1, Xx2, Px00, Px01, Px02, Px11, Px12, Px22,
               qsx*gx00, qsx*gx01, qsx*gx02, qsx*gx11, qsx*gx12, qsx*gx22);
        kpred9(Xy0, Xy1, Xy2, Py00, Py01, Py02, Py11, Py12, Py22,
               qsy*gy00, qsy*gy01, qsy*gy02, qsy*gy11, qsy*gy12, qsy*gy22);
        if (wv == 6 && q == 0) {
            float* o = out + (size_t)be * (LEN_PRED * 5) + tout * 5;
            o[0] = Xx0; o[1] = Xy0; o[2] = sqrtf(Px00); o[3] = sqrtf(Py00); o[4] = 0.f;
        }
    };

    // ---- LDS zero init (h,c = 0 for both parities) ----
    for (int i = tid; i < 3 * 2 * 4 * 16 * 4; i += 512) {
        (&xchC[0][0][0][0][0])[i] = 0;
        (&xchH[0][0][0][0][0])[i] = 0;
    }

    // ---- prologue: waves 6,7 run encoder KF + Win fully in-register ----
    if (wv >= 6) {
#pragma unroll 1
        for (int s = 0; s < T_HIST - 1; ++s) {
            if (s > 0) kf_enc_step(s);
            win_emit(&xenc[s][0][0][0]);
        }
        kf_enc_step(T_HIST - 1);   // z_19 -> decoder-initial KF state (stays in regs)
    }
    __syncthreads();               // xenc + zero-init visible

    // ---- encoder: diagonal pipeline, phases p = 0..20, ONE barrier each ----
#pragma unroll 1
    for (int p = 0; p < T_HIST + 1; ++p) {
        const int pw = p & 1, pr = pw ^ 1;
        if (p <= T_HIST - 2) {
            bfrag8 xf = *(const bfrag8*)&xenc[p][q][m][0];
            bfrag8 hf = *(const bfrag8*)&xchH[0][pr][q][m][0];
            cell(0, xf, hf, &xchC[0][pw][0][0][0], &xchH[0][pw][0][0][0]);
        }
        if (p >= 1 && p <= T_HIST - 1) {
            bfrag8 xf = *(const bfrag8*)&xchC[0][pr][q][m][0];
            bfrag8 hf = *(const bfrag8*)&xchH[1][pr][q][m][0];
            cell(1, xf, hf, &xchC[1][pw][0][0][0], &xchH[1][pw][0][0][0]);
        }
        if (p >= 2) {
            bfrag8 xf = *(const bfrag8*)&xchC[1][pr][q][m][0];
            bfrag8 hf = *(const bfrag8*)&xchH[2][pr][q][m][0];
            cell(2, xf, hf, &xchC[2][pw][0][0][0], &xchH[2][pw][0][0][0]);
        }
        __syncthreads();
    }

    // ---- transition: final h frags / c2 from pipeline parities ----
    // h0[18] @p18(par0), h1[18] @p19(par1), h2[18]/c2[18] @p20(par0)
    load_phase(1);
    bfrag8 hfragR[3];
    hfragR[0] = *(const bfrag8*)&xchH[0][0][q][m][0];
    hfragR[1] = *(const bfrag8*)&xchH[1][1][q][m][0];
    hfragR[2] = *(const bfrag8*)&xchH[2][0][q][m][0];
    c2f       = *(const bfrag8*)&xchC[2][0][q][m][0];
    // (first decoder write to these buffers is after bar1 -> reads are safe)

    // ---- decoder: 30 steps, 4 barriers/step ----
#pragma unroll 1
    for (int t = 0; t < LEN_PRED; ++t) {
        f32x4 ah[3];
#pragma unroll
        for (int l = 0; l < 3; ++l)    // hoisted hh-MFMAs (h(t-1) in registers)
            ah[l] = __builtin_amdgcn_mfma_f32_16x16x32_bf16(fragA[l][1], hfragR[l], biasV[l], 0, 0, 0);

        if (wv >= 6) {
            if (t > 0) do_pred(t - 1); // Wout (replicated) -> KF pred -> out store
            win_emit(&x0b[0][0][0]);   // XP in regs -> Win MFMA -> x0
        }
        __syncthreads();   // bar1: x0 visible

        bfrag8 xf = *(const bfrag8*)&x0b[q][m][0];
#pragma unroll
        for (int l = 0; l < 3; ++l) {
            f32x4 a = __builtin_amdgcn_mfma_f32_16x16x32_bf16(fragA[l][0], xf, ah[l], 0, 0, 0);
            float iv = sig(a[0]), fv = sig(a[1]), gv = th(a[2]), ov = sig(a[3]);
            float c = fmaf(fv, creg[l], iv * gv);
            creg[l] = c;
            float h = ov * th(c);
            unsigned int pk = cvtpk(c, h);
            ((unsigned short*)&xchC[l][0][0][0][0])[sidx] = (unsigned short)pk;
            ((unsigned short*)&xchH[l][0][0][0][0])[sidx] = (unsigned short)(pk >> 16);
            __syncthreads();   // bar2..4
            xf        = *(const bfrag8*)&xchC[l][0][q][m][0];
            hfragR[l] = *(const bfrag8*)&xchH[l][0][q][m][0];
        }
        c2f = xf;
    }
    if (wv >= 6) do_pred(LEN_PRED - 1);
}

extern "C" void kernel_launch(void* const* d_in, const int* in_sizes, int n_in,
                              void* d_out, int out_size, void* d_ws, size_t ws_size,
                              hipStream_t stream)
{
    const float* hist  = (const float*)d_in[0];
    const float* maxax = (const float*)d_in[1];
    const float* maxay = (const float*)d_in[2];
    const float* vstd  = (const float*)d_in[3];
    const float* astd  = (const float*)d_in[4];
    const float* Rx    = (const float*)d_in[5];
    const float* Ry    = (const float*)d_in[6];
    const float* Gx    = (const float*)d_in[7];
    const float* Gy    = (const float*)d_in[8];
    const float* WinW  = (const float*)d_in[9];
    const float* Winb  = (const float*)d_in[10];
    const float* eWih  = (const float*)d_in[11];
    const float* eWhh  = (const float*)d_in[12];
    const float* ebih  = (const float*)d_in[13];
    const float* ebhh  = (const float*)d_in[14];
    const float* dWih  = (const float*)d_in[15];
    const float* dWhh  = (const float*)d_in[16];
    const float* dbih  = (const float*)d_in[17];
    const float* dbhh  = (const float*)d_in[18];
    const float* WoutW = (const float*)d_in[19];
    const float* Woutb = (const float*)d_in[20];
    char* ws = (char*)d_ws;
    float* out = (float*)d_out;

    prep_kernel<<<202, 256, 0, stream>>>(WinW, eWih, eWhh, ebih, ebhh,
                                         dWih, dWhh, dbih, dbhh, WoutW, ws);
    kalman_lstm_kernel<<<512, 512, 0, stream>>>(hist, maxax, maxay, vstd, astd,
                                                Rx, Ry, Gx, Gy, Winb, Woutb,
                                                ws, out);
}